// Round 1
// 82.400 us; speedup vs baseline: 1.0024x; 1.0024x over previous
//
#include <hip/hip_runtime.h>

namespace {
constexpr int NA   = 128;
constexpr int NC2  = NA * (NA - 1) / 2;          // 8128
constexpr int R    = 4;                          // batch rows per block
constexpr int SEGS = 4;                          // pair-space segments per row-group
constexpr int SEG  = NC2 / SEGS;                 // 2032 (8128 = 4*2032 exactly)
constexpr int BT   = 256;                        // threads per block
constexpr float SCALE = 627.5095f * 0.529177f / 100.0f;  // AU2KCALMOLA / MAX_NRF
}

// Triangle packing: pair-slot q in [0, NC2). Chunk u = q>>7 (128 slots)
// covers row a=u+1 (slots r<a -> pair (a,r)) and row b=127-u (slots r>=a ->
// pair (b, r-a)); a+b=128 exactly, so packing is waste-free and index math
// is ~10 int ops (no sqrt, no loops). Within a wave, i takes at most 2
// values -> LDS broadcast (free); j is consecutive per segment -> conflict-
// free ds_read_b128. Output position p = tri(i)+j gives <=2 contiguous store
// segments per wave -> coalesced 256B bursts.
//
// v2 change: occupancy 2x. Old config (512 blk x 512 thr) was only
// 2 blocks/CU = 16 waves/CU (50%); the per-iteration dependent chain
// (index math -> atoms L2 load ~200cy + ds_read ~120cy -> rcp -> store)
// was latency-bound at ~1.8 TB/s effective. Now 2048 blk x 256 thr =
// 8 blocks/CU, 32 waves/CU (100%). R=4 batch-row amortization of index
// math + atoms reads is KEPT by splitting pair-space 4 ways instead of
// shrinking R. __launch_bounds__(256,8) caps VGPR at 64 for 8 waves/SIMD.
__global__ __launch_bounds__(BT, 8) void nrf_kernel(
    const float* __restrict__ coords,
    const float* __restrict__ atoms,
    float* __restrict__ out)
{
    __shared__ float4 c4[R][NA];
    const int bid = blockIdx.x;
    const int b0  = (bid >> 2) * R;          // batch row group
    const int q0  = (bid & 3) * SEG;         // pair-space segment [q0, qe)
    const int qe  = q0 + SEG;
    const int tid = threadIdx.x;

    // Stage R rows (R*NA*3 contiguous floats) -> AoS float4 (x,y,z,pad).
    const float* cb = coords + (size_t)b0 * (NA * 3);
    float* c4f = reinterpret_cast<float*>(&c4[0][0]);
    for (int k = tid; k < R * NA * 3; k += BT) {
        int atom = k / 3;                 // constant div -> magic mul
        int comp = k - atom * 3;
        c4f[atom * 4 + comp] = cb[k];     // c4 is row-major, matches flat atom
    }
    __syncthreads();

    float* outb = out + (size_t)b0 * NC2;

    // 2032/256 -> 8 iterations per thread (last one 16/64 lanes masked).
    for (int q = q0 + tid; q < qe; q += BT) {
        int u = q >> 7;
        int r = q & 127;
        int a = u + 1;
        bool lo = (r < a);
        int i = lo ? a : 127 - u;
        int j = lo ? r : r - a;
        int p = ((i * (i - 1)) >> 1) + j;

        float av = atoms[p] * SCALE;      // once per R rows

        float* o = outb + p;
        #pragma unroll
        for (int m = 0; m < R; ++m) {
            float4 ci = c4[m][i];         // <=2 distinct values/wave -> bcast
            float4 cj = c4[m][j];         // lane-consecutive -> conflict-free
            float dx = ci.x - cj.x;
            float dy = ci.y - cj.y;
            float dz = ci.z - cj.z;
            float d2 = dx * dx + dy * dy + dz * dz;
            // ref: 1/(sqrt(d2))^2 == 1/d2 within ~2 ulp; v_rcp_f32 is 1 ulp
            o[(size_t)m * NC2] = av * __builtin_amdgcn_rcpf(d2);
        }
    }
}

extern "C" void kernel_launch(void* const* d_in, const int* in_sizes, int n_in,
                              void* d_out, int out_size, void* d_ws, size_t ws_size,
                              hipStream_t stream)
{
    const float* coords = (const float*)d_in[0];
    const float* atoms  = (const float*)d_in[1];
    float*       out    = (float*)d_out;
    const int batch = in_sizes[0] / (NA * 3);    // 2048
    nrf_kernel<<<(batch / R) * SEGS, BT, 0, stream>>>(coords, atoms, out);
}